// Round 15
// baseline (511.826 us; speedup 1.0000x reference)
//
#include <hip/hip_runtime.h>
#include <stdint.h>

#define TSTEPS 1024
#define S 4          // timesteps per super-iter (layer skew)
#define NK 258       // 1024/S + 2 pipeline-drain super-iters
#define L2E 1.4426950408889634f

typedef float v2f __attribute__((ext_vector_type(2)));
typedef float v4f __attribute__((ext_vector_type(4)));

__device__ __forceinline__ float rcpf_(float v) { return __builtin_amdgcn_rcpf(v); }
__device__ __forceinline__ float ex2(float v) { return __builtin_amdgcn_exp2f(v); }
#define PKFMA(a, b, c) __builtin_elementwise_fma((a), (b), (c))

// Opaque loads: value is asm-produced -> cannot be rematerialized as a load.
__device__ __forceinline__ v2f ldg2(const float* p) {
    v2f r; uint64_t a = (uint64_t)p;
    asm volatile("global_load_dwordx2 %0, %1, off\n\ts_waitcnt vmcnt(0)"
                 : "=v"(r) : "v"(a));
    return r;
}
__device__ __forceinline__ float ldg1(const float* p) {
    float r; uint64_t a = (uint64_t)p;
    asm volatile("global_load_dword %0, %1, off\n\ts_waitcnt vmcnt(0)"
                 : "=v"(r) : "v"(a));
    return r;
}

// read 16 consecutive LDS floats (broadcast within seq group) into 8 v2f
#define RDH(dst, p)                                                        \
    do {                                                                   \
        v4f a0 = *(const v4f*)(p);                                         \
        v4f a1 = *(const v4f*)((p) + 4);                                   \
        v4f a2 = *(const v4f*)((p) + 8);                                   \
        v4f a3 = *(const v4f*)((p) + 12);                                  \
        dst[0] = __builtin_shufflevector(a0, a0, 0, 1);                    \
        dst[1] = __builtin_shufflevector(a0, a0, 2, 3);                    \
        dst[2] = __builtin_shufflevector(a1, a1, 0, 1);                    \
        dst[3] = __builtin_shufflevector(a1, a1, 2, 3);                    \
        dst[4] = __builtin_shufflevector(a2, a2, 0, 1);                    \
        dst[5] = __builtin_shufflevector(a2, a2, 2, 3);                    \
        dst[6] = __builtin_shufflevector(a3, a3, 0, 1);                    \
        dst[7] = __builtin_shufflevector(a3, a3, 2, 3);                    \
    } while (0)

#define DOT8(w, h, seed)                                                   \
    ({                                                                     \
        v2f _a = PKFMA(w[0], h[0], (seed));                                \
        _a = PKFMA(w[1], h[1], _a); _a = PKFMA(w[2], h[2], _a);            \
        _a = PKFMA(w[3], h[3], _a); _a = PKFMA(w[4], h[4], _a);            \
        _a = PKFMA(w[5], h[5], _a); _a = PKFMA(w[6], h[6], _a);            \
        _a = PKFMA(w[7], h[7], _a);                                        \
        _a.x + _a.y;                                                       \
    })

// Roles: wave0 = L0 (+V1-partials for L1), wave1 = L1 (+V2-partials for L2),
// wave2 = L2. Cross-layer handoff = 3 scalar gate-partials per unit per step
// (biases folded producer-side), through double-buffered rings with one
// barrier per S-step super-iter. Own-layer recurrence: same-wave LDS
// scratch write -> broadcast b128 read (program-ordered, barrier-free).
__global__ __launch_bounds__(192, 3)
__attribute__((amdgpu_waves_per_eu(3, 3)))
void gru3_po(
    const float* __restrict__ x,      // [4096,1024,1]
    const float* __restrict__ w_ih0,  // [48,1]
    const float* __restrict__ w_ih12, // [2,48,16]
    const float* __restrict__ w_hh,   // [3,48,16]
    const float* __restrict__ b_ih,   // [3,48]
    const float* __restrict__ b_hh,   // [3,48]
    const float* __restrict__ fc_w,   // [5,16]
    const float* __restrict__ fc_b,   // [5]
    float* __restrict__ out)          // [4096,5]
{
    // [link: 0=p1(L0->L1), 1=p2(L1->L2)][buf][j][s][gate*16+u]
    // bank check (48-float s-stride): bank = (16s+16g+u)%32 -> 2 lanes/bank.
    __shared__ float pring[2][2][S][4][48];  // 24576 B
    __shared__ float hscr[3][4][16];         // own-recurrence scratch, 768 B

    const int tid = threadIdx.x;
    const int role = tid >> 6;
    const int lane = tid & 63;
    const int s = lane >> 4;           // seq within block (0..3)
    const int u = lane & 15;           // hidden unit
    const int seq = blockIdx.x * 4 + s;

    ((float*)hscr)[tid] = 0.f;  // h(-1) = 0; pring needs no init (WAR by K-window)
    __syncthreads();

    if (role == 0) {
        // ---- L0 gates (w_hh[0], w_ih0) + V1-partials (w_ih12[0], L1 biases)
        v2f wr[8], wz[8], wn[8], v1r[8], v1z[8], v1n[8];
#pragma unroll
        for (int m = 0; m < 8; ++m) {
            wr[m] = ldg2(w_hh + (u) * 16 + 2 * m) * -L2E;
            wz[m] = ldg2(w_hh + (16 + u) * 16 + 2 * m) * -L2E;
            wn[m] = ldg2(w_hh + (32 + u) * 16 + 2 * m) * (2.f * L2E);
            v1r[m] = ldg2(w_ih12 + (u) * 16 + 2 * m) * -L2E;
            v1z[m] = ldg2(w_ih12 + (16 + u) * 16 + 2 * m) * -L2E;
            v1n[m] = ldg2(w_ih12 + (32 + u) * 16 + 2 * m) * (2.f * L2E);
        }
        const float wxr = ldg1(w_ih0 + u) * -L2E;
        const float wxz = ldg1(w_ih0 + 16 + u) * -L2E;
        const float wxn = ldg1(w_ih0 + 32 + u) * (2.f * L2E);
        const v2f sbr = {-(ldg1(b_ih + u) + ldg1(b_hh + u)) * L2E, 0.f};
        const v2f sbz = {-(ldg1(b_ih + 16 + u) + ldg1(b_hh + 16 + u)) * L2E, 0.f};
        const v2f sbn = {ldg1(b_hh + 32 + u) * (2.f * L2E), 0.f};
        const float bnx = ldg1(b_ih + 32 + u) * (2.f * L2E);
        // L1 gate biases ride the V1-partials (consumer adds nothing)
        const v2f s1r = {-(ldg1(b_ih + 48 + u) + ldg1(b_hh + 48 + u)) * L2E, 0.f};
        const v2f s1z = {-(ldg1(b_ih + 64 + u) + ldg1(b_hh + 64 + u)) * L2E, 0.f};
        const v2f s1x = {ldg1(b_ih + 80 + u) * (2.f * L2E), 0.f};

        const float* xp = x + (size_t)seq * TSTEPS;
        const float* hr = &hscr[0][s][0];
        float* pc = &pring[0][0][0][s][0];  // write buf = K&1, starts 0
        float* pp = &pring[0][1][0][s][0];
        float hown = 0.f;
        v4f xq = *(const v4f*)xp;
        for (int K = 0; K < NK; ++K) {
            if (K < 256) {
                v4f xqn = *(const v4f*)(xp + 4 * ((K < 255) ? K + 1 : 255));
#pragma unroll
                for (int j = 0; j < S; ++j) {
                    v2f hp[8];
                    RDH(hp, hr);  // h0(t-1) replicated
                    float xt = xq[j];
                    float sr = fmaf(wxr, xt, DOT8(wr, hp, sbr));
                    float sz = fmaf(wxz, xt, DOT8(wz, hp, sbz));
                    float snh = DOT8(wn, hp, sbn);
                    float r = rcpf_(1.f + ex2(sr));
                    float z = rcpf_(1.f + ex2(sz));
                    float ut = fmaf(r, snh, fmaf(wxn, xt, bnx));
                    float n = fmaf(-2.f, rcpf_(ex2(ut) + 1.f), 1.f);
                    hown = fmaf(z, hown - n, n);
                    hscr[0][s][u] = hown;
                    v2f hq[8];
                    RDH(hq, hr);  // h0(t) replicated (same-wave ordered)
                    float pr = DOT8(v1r, hq, s1r);
                    float pz = DOT8(v1z, hq, s1z);
                    float px = DOT8(v1n, hq, s1x);
                    float* pb = pc + j * (4 * 48);
                    pb[u] = pr; pb[16 + u] = pz; pb[32 + u] = px;
                }
                xq = xqn;
            }
            __syncthreads();
            float* t_ = pc; pc = pp; pp = t_;
        }
    } else if (role == 1) {
        // ---- L1 gates (w_hh[1] + partials) + V2-partials (w_ih12[1], L2 biases)
        v2f wr[8], wz[8], wn[8], v2r[8], v2z[8], v2n[8];
#pragma unroll
        for (int m = 0; m < 8; ++m) {
            wr[m] = ldg2(w_hh + (48 + u) * 16 + 2 * m) * -L2E;
            wz[m] = ldg2(w_hh + (48 + 16 + u) * 16 + 2 * m) * -L2E;
            wn[m] = ldg2(w_hh + (48 + 32 + u) * 16 + 2 * m) * (2.f * L2E);
            v2r[m] = ldg2(w_ih12 + (48 + u) * 16 + 2 * m) * -L2E;
            v2z[m] = ldg2(w_ih12 + (48 + 16 + u) * 16 + 2 * m) * -L2E;
            v2n[m] = ldg2(w_ih12 + (48 + 32 + u) * 16 + 2 * m) * (2.f * L2E);
        }
        const v2f sbn = {ldg1(b_hh + 80 + u) * (2.f * L2E), 0.f};
        const v2f s2r = {-(ldg1(b_ih + 96 + u) + ldg1(b_hh + 96 + u)) * L2E, 0.f};
        const v2f s2z = {-(ldg1(b_ih + 112 + u) + ldg1(b_hh + 112 + u)) * L2E, 0.f};
        const v2f s2x = {ldg1(b_ih + 128 + u) * (2.f * L2E), 0.f};

        const float* hr = &hscr[1][s][0];
        const float* in0 = &pring[0][0][0][s][0];
        const float* in1 = &pring[0][1][0][s][0];
        float* my0 = &pring[1][0][0][s][0];
        float* my1 = &pring[1][1][0][s][0];
        const float* inp = in1;  // at K reads (K-1)&1 after first swap
        float* mycur = my0; float* myprv = my1;
        float hown = 0.f;
        for (int K = 0; K < NK; ++K) {
            if (K >= 1 && K < 257) {
#pragma unroll
                for (int j = 0; j < S; ++j) {
                    const float* qb = inp + j * (4 * 48);
                    float pr = qb[u], pz = qb[16 + u], px = qb[32 + u];
                    v2f hp[8];
                    RDH(hp, hr);  // h1(t-1)
                    float sr = DOT8(wr, hp, ((v2f){pr, 0.f}));
                    float sz = DOT8(wz, hp, ((v2f){pz, 0.f}));
                    float snh = DOT8(wn, hp, sbn);
                    float r = rcpf_(1.f + ex2(sr));
                    float z = rcpf_(1.f + ex2(sz));
                    float ut = fmaf(r, snh, px);
                    float n = fmaf(-2.f, rcpf_(ex2(ut) + 1.f), 1.f);
                    hown = fmaf(z, hown - n, n);
                    hscr[1][s][u] = hown;
                    v2f hq[8];
                    RDH(hq, hr);  // h1(t) replicated
                    float qr = DOT8(v2r, hq, s2r);
                    float qz = DOT8(v2z, hq, s2z);
                    float qx = DOT8(v2n, hq, s2x);
                    float* pb = mycur + j * (4 * 48);
                    pb[u] = qr; pb[16 + u] = qz; pb[32 + u] = qx;
                }
            }
            __syncthreads();
            const float* t0 = (inp == in0) ? in1 : in0; inp = t0;
            float* t1 = mycur; mycur = myprv; myprv = t1;
        }
    } else {
        // ---- L2 gates (w_hh[2] + partials); head at the end
        v2f wr[8], wz[8], wn[8];
#pragma unroll
        for (int m = 0; m < 8; ++m) {
            wr[m] = ldg2(w_hh + (96 + u) * 16 + 2 * m) * -L2E;
            wz[m] = ldg2(w_hh + (96 + 16 + u) * 16 + 2 * m) * -L2E;
            wn[m] = ldg2(w_hh + (96 + 32 + u) * 16 + 2 * m) * (2.f * L2E);
        }
        const v2f sbn = {ldg1(b_hh + 128 + u) * (2.f * L2E), 0.f};

        const float* hr = &hscr[2][s][0];
        const float* in0 = &pring[1][0][0][s][0];
        const float* in1 = &pring[1][1][0][s][0];
        const float* inp = in1;
        float hown = 0.f;
        for (int K = 0; K < NK; ++K) {
            if (K >= 2) {
#pragma unroll
                for (int j = 0; j < S; ++j) {
                    const float* qb = inp + j * (4 * 48);
                    float pr = qb[u], pz = qb[16 + u], px = qb[32 + u];
                    v2f hp[8];
                    RDH(hp, hr);  // h2(t-1)
                    float sr = DOT8(wr, hp, ((v2f){pr, 0.f}));
                    float sz = DOT8(wz, hp, ((v2f){pz, 0.f}));
                    float snh = DOT8(wn, hp, sbn);
                    float r = rcpf_(1.f + ex2(sr));
                    float z = rcpf_(1.f + ex2(sz));
                    float ut = fmaf(r, snh, px);
                    float n = fmaf(-2.f, rcpf_(ex2(ut) + 1.f), 1.f);
                    hown = fmaf(z, hown - n, n);
                    hscr[2][s][u] = hown;
                }
            }
            __syncthreads();
            const float* t0 = (inp == in0) ? in1 : in0; inp = t0;
        }
        // ---- head on h2(1023): replicated read from scratch (same-wave)
        v2f hf[8];
        RDH(hf, hr);
        const int ur = (u < 5) ? u : 0;
        v2f fw[8];
#pragma unroll
        for (int m = 0; m < 8; ++m) fw[m] = ldg2(fc_w + ur * 16 + 2 * m);
        float acc = ldg1(fc_b + ur) + DOT8(fw, hf, ((v2f){0.f, 0.f}));
        if (u < 5) out[seq * 5 + u] = acc;
    }
}

extern "C" void kernel_launch(void* const* d_in, const int* in_sizes, int n_in,
                              void* d_out, int out_size, void* d_ws, size_t ws_size,
                              hipStream_t stream) {
    const float* x      = (const float*)d_in[0];
    const float* w_ih0  = (const float*)d_in[1];
    const float* w_ih12 = (const float*)d_in[2];
    const float* w_hh   = (const float*)d_in[3];
    const float* b_ih   = (const float*)d_in[4];
    const float* b_hh   = (const float*)d_in[5];
    const float* fc_w   = (const float*)d_in[6];
    const float* fc_b   = (const float*)d_in[7];
    float* out = (float*)d_out;

    // 1024 blocks x 192 threads (3 role waves, 4 seqs/block)
    gru3_po<<<1024, 192, 0, stream>>>(
        x, w_ih0, w_ih12, w_hh, b_ih, b_hh, fc_w, fc_b, out);
}